// Round 3
// baseline (288.739 us; speedup 1.0000x reference)
//
#include <hip/hip_runtime.h>
#include <hip/hip_bf16.h>

#define B_    1024
#define NHID_ 4096
#define NBO   8
#define BSO   512
#define DK_   64

typedef __bf16 bf16;
typedef __bf16 bf16x2 __attribute__((ext_vector_type(2)));
typedef __bf16 bf16x4 __attribute__((ext_vector_type(4)));
typedef __bf16 bf16x8 __attribute__((ext_vector_type(8)));
typedef float  f32x4  __attribute__((ext_vector_type(4)));

__device__ __forceinline__ float sigf(float x){
    float e = __expf(-x);
    return __builtin_amdgcn_rcpf(1.0f + e);
}
__device__ __forceinline__ float ftanh(float x){
    float e = __expf(2.0f*x);
    return 1.0f - 2.0f*__builtin_amdgcn_rcpf(e + 1.0f);
}

// async global->LDS, 16B per lane; lds dest is wave-uniform base (+lane*16 implicit)
__device__ __forceinline__ void gload16(const void* g, void* lds){
    __builtin_amdgcn_global_load_lds((const __attribute__((address_space(1))) unsigned int*)g,
                                     (__attribute__((address_space(3))) unsigned int*)lds,
                                     16, 0, 0);
}

// raw barrier without the compiler's vmcnt(0) drain; empty asm pins memory ops
__device__ __forceinline__ void sbar(){
    asm volatile("" ::: "memory");
    __builtin_amdgcn_s_barrier();
    asm volatile("" ::: "memory");
}
#define WAITVM(N) asm volatile("s_waitcnt vmcnt(" #N ")" ::: "memory")

// ---------------------------------------------------------------- merged prep:
// blocks < 4096: w_ih/w_hh -> bf16 transposed wT[n][gcol2048][k1024]
// blocks >= 4096: hx->bf16, mha qkv weight transpose, ia_fc transpose, fc|gate paired transpose
__global__ __launch_bounds__(256) void k_prep(
    const float* __restrict__ w_ih, const float* __restrict__ w_hh,
    const float* __restrict__ hx,
    const float* __restrict__ mha_wq, const float* __restrict__ mha_wk,
    const float* __restrict__ mha_wv, const float* __restrict__ ia_fc_w,
    const float* __restrict__ fc_w, const float* __restrict__ gate_w,
    bf16* __restrict__ wT, bf16* __restrict__ hb16, bf16* __restrict__ wqkvT,
    bf16* __restrict__ iafcT, bf16* __restrict__ fcgT)
{
    int bid = blockIdx.x;
    int t = threadIdx.x;
    if (bid < 4096){
        int c0 = (bid & 31)*64;
        int k0 = ((bid>>5)&7)*64;
        int z  = bid>>8;
        int n = z>>1, which = z&1;
        const float* src = (which ? w_hh : w_ih) + (size_t)n*512*2048;
        __shared__ float tile[64][65];
        #pragma unroll
        for (int it=0; it<4; ++it){
            int idx = t + it*256;
            int r = idx>>4, c4 = (idx&15)*4;
            *(float4*)&tile[r][c4] = *(const float4*)&src[(size_t)(k0+r)*2048 + c0 + c4];
        }
        __syncthreads();
        #pragma unroll
        for (int it=0; it<2; ++it){
            int idx = t + it*256;
            int c = idx>>3, r8 = (idx&7)*8;
            bf16x8 v;
            #pragma unroll
            for (int jj=0;jj<8;++jj) v[jj] = (bf16)tile[r8+jj][c];
            *(bf16x8*)&wT[((size_t)n*2048 + c0 + c)*1024 + which*512 + k0 + r8] = v;
        }
        return;
    }
    int gid = (bid-4096)*256 + t;
    if (gid < 1048576){
        float4 v = ((const float4*)hx)[gid];
        bf16x4 o; o.x=(bf16)v.x; o.y=(bf16)v.y; o.z=(bf16)v.z; o.w=(bf16)v.w;
        *(bf16x4*)&hb16[(size_t)gid*4] = o;
        return;
    }
    int e = gid - 1048576;
    if (e < 786432){   // wqkvT[(n*192+c)*512 + k]
        int col = e >> 9, k = e & 511;
        int n = col / 192, c = col - n*192;
        int p = c >> 6, ee = c & 63;
        const float* s = (p==0) ? mha_wq : ((p==1) ? mha_wk : mha_wv);
        wqkvT[e] = (bf16)s[((size_t)n*512 + k)*64 + ee];
        return;
    }
    e -= 786432;
    if (e < 32768){
        int c = e>>6, k = e&63;
        iafcT[e] = (bf16)ia_fc_w[(size_t)k*512 + c];
        return;
    }
    e -= 32768;
    if (e < 65536){
        int cg = e>>6, k = e&63;
        int ct = cg>>6, j = cg&63;
        const float* s = (j<32) ? fc_w : gate_w;
        int col = ct*32 + (j&31);
        fcgT[e] = (bf16)s[(size_t)k*512 + col];
    }
}

// ---------------------------------------------------------------- q / k / v input-attn GEMMs (fp32 exact)
// grid (32 Mtiles of 32 rows, 12): y<8 -> q for n=y; else kv for j=y-8
__global__ __launch_bounds__(256) void k_qkv(const float* __restrict__ hx,
                                             const float* __restrict__ inp,
                                             const float* __restrict__ ia_wq,
                                             const float* __restrict__ ia_wk,
                                             const float* __restrict__ ia_wv,
                                             float* __restrict__ qbuf,
                                             float* __restrict__ kbuf,
                                             float* __restrict__ vbuf)
{
    int b0 = blockIdx.x*32, y = blockIdx.y, t = threadIdx.x;
    int tx = t&15, ty = t>>4;
    __shared__ float Af[32][36];
    __shared__ float W1[32][68];
    __shared__ float W2[32][68];
    if (y < 8){
        int n = y;
        float acc[2][4] = {};
        for (int k0=0; k0<512; k0+=32){
            { int row=t>>3, c4=(t&7)*4;
              *(float4*)&Af[row][c4] = *(const float4*)&hx[(size_t)(b0+row)*4096 + n*512 + k0 + c4]; }
            #pragma unroll
            for (int j=0;j<2;++j){
                int id = j*256 + t;
                int kk = id>>4, e4 = (id&15)*4;
                *(float4*)&W1[kk][e4] = *(const float4*)&ia_wq[(size_t)n*32768 + (size_t)(k0+kk)*64 + e4];
            }
            __syncthreads();
            #pragma unroll
            for (int kk4=0; kk4<8; ++kk4){
                float4 a0 = *(float4*)&Af[ty*2  ][kk4*4];
                float4 a1 = *(float4*)&Af[ty*2+1][kk4*4];
                #pragma unroll
                for (int j=0;j<4;++j){
                    float4 wv = *(float4*)&W1[kk4*4+j][tx*4];
                    float s0 = (j==0)?a0.x:((j==1)?a0.y:((j==2)?a0.z:a0.w));
                    float s1 = (j==0)?a1.x:((j==1)?a1.y:((j==2)?a1.z:a1.w));
                    acc[0][0]+=s0*wv.x; acc[0][1]+=s0*wv.y; acc[0][2]+=s0*wv.z; acc[0][3]+=s0*wv.w;
                    acc[1][0]+=s1*wv.x; acc[1][1]+=s1*wv.y; acc[1][2]+=s1*wv.z; acc[1][3]+=s1*wv.w;
                }
            }
            __syncthreads();
        }
        #pragma unroll
        for (int r=0;r<2;++r){
            float4 o; o.x=acc[r][0]; o.y=acc[r][1]; o.z=acc[r][2]; o.w=acc[r][3];
            *(float4*)&qbuf[(size_t)(b0+ty*2+r)*512 + n*64 + tx*4] = o;
        }
    } else {
        int jb = y-8;
        float ak[2][4] = {}, av[2][4] = {};
        for (int k0=0; k0<128; k0+=32){
            { int row=t>>3, c4=(t&7)*4;
              *(float4*)&Af[row][c4] = *(const float4*)&inp[(size_t)(b0+row)*512 + jb*128 + k0 + c4]; }
            #pragma unroll
            for (int j=0;j<2;++j){
                int id = j*256 + t;
                int kk = id>>4, e4 = (id&15)*4;
                *(float4*)&W1[kk][e4] = *(const float4*)&ia_wk[(size_t)jb*8192 + (size_t)(k0+kk)*64 + e4];
                *(float4*)&W2[kk][e4] = *(const float4*)&ia_wv[(size_t)jb*8192 + (size_t)(k0+kk)*64 + e4];
            }
            __syncthreads();
            #pragma unroll
            for (int kk4=0; kk4<8; ++kk4){
                float4 a0 = *(float4*)&Af[ty*2  ][kk4*4];
                float4 a1 = *(float4*)&Af[ty*2+1][kk4*4];
                #pragma unroll
                for (int j=0;j<4;++j){
                    float4 wk = *(float4*)&W1[kk4*4+j][tx*4];
                    float4 wv = *(float4*)&W2[kk4*4+j][tx*4];
                    float s0 = (j==0)?a0.x:((j==1)?a0.y:((j==2)?a0.z:a0.w));
                    float s1 = (j==0)?a1.x:((j==1)?a1.y:((j==2)?a1.z:a1.w));
                    ak[0][0]+=s0*wk.x; ak[0][1]+=s0*wk.y; ak[0][2]+=s0*wk.z; ak[0][3]+=s0*wk.w;
                    ak[1][0]+=s1*wk.x; ak[1][1]+=s1*wk.y; ak[1][2]+=s1*wk.z; ak[1][3]+=s1*wk.w;
                    av[0][0]+=s0*wv.x; av[0][1]+=s0*wv.y; av[0][2]+=s0*wv.z; av[0][3]+=s0*wv.w;
                    av[1][0]+=s1*wv.x; av[1][1]+=s1*wv.y; av[1][2]+=s1*wv.z; av[1][3]+=s1*wv.w;
                }
            }
            __syncthreads();
        }
        #pragma unroll
        for (int r=0;r<2;++r){
            float4 ok; ok.x=ak[r][0]; ok.y=ak[r][1]; ok.z=ak[r][2]; ok.w=ak[r][3];
            float4 ov; ov.x=av[r][0]; ov.y=av[r][1]; ov.z=av[r][2]; ov.w=av[r][3];
            *(float4*)&kbuf[(size_t)(b0+ty*2+r)*256 + jb*64 + tx*4] = ok;
            *(float4*)&vbuf[(size_t)(b0+ty*2+r)*256 + jb*64 + tx*4] = ov;
        }
    }
}

// ---------------------------------------------------------------- scores + softmax + top4 + o
__global__ __launch_bounds__(256) void k_score(const float* __restrict__ qbuf,
                                               const float* __restrict__ kbuf,
                                               const float* __restrict__ vbuf,
                                               bf16* __restrict__ obuf,
                                               float* __restrict__ maskb,
                                               float* __restrict__ mask_out)
{
    int t = threadIdx.x, sb = t>>6, ts = t&63;
    int b = blockIdx.x*4 + sb;
    __shared__ float q_s[4][512];
    __shared__ float k_s[4][256];
    __shared__ float v_s[4][256];
    __shared__ float at_s[4][40];
    __shared__ float sc_s[4][8];
    __shared__ float mb_s[4][8];

    #pragma unroll
    for (int r=0;r<8;++r) q_s[sb][ts+r*64] = qbuf[(size_t)b*512 + ts + r*64];
    #pragma unroll
    for (int r=0;r<4;++r){
        k_s[sb][ts+r*64] = kbuf[(size_t)b*256 + ts + r*64];
        v_s[sb][ts+r*64] = vbuf[(size_t)b*256 + ts + r*64];
    }
    __syncthreads();
    if (ts < 40){
        int n = ts/5, j = ts%5;
        float s = 0.f;
        if (j < 4){
            const float* q = &q_s[sb][n*64];
            const float* k = &k_s[sb][j*64];
            for (int e=0;e<64;++e) s += q[e]*k[e];
            s *= 0.125f;
        }
        at_s[sb][ts] = s;
    }
    __syncthreads();
    if (ts < 8){
        float m = at_s[sb][ts*5];
        for (int j=1;j<5;++j) m = fmaxf(m, at_s[sb][ts*5+j]);
        float ex[5]; float sum=0.f;
        for (int j=0;j<5;++j){ ex[j]=__expf(at_s[sb][ts*5+j]-m); sum+=ex[j]; }
        float inv = 1.f/sum;
        for (int j=0;j<5;++j) at_s[sb][ts*5+j] = ex[j]*inv;
        sc_s[sb][ts] = ex[0]*inv;
    }
    __syncthreads();
    if (ts == 0){
        float s[8];
        for (int nn=0;nn<8;++nn) s[nn] = sc_s[sb][nn];
        for (int ii=1;ii<8;++ii){ float key=s[ii]; int jj=ii-1;
            while(jj>=0 && s[jj]<key){ s[jj+1]=s[jj]; --jj; } s[jj+1]=key; }
        float thr = s[3]-0.01f;
        for (int nn=0;nn<8;++nn) mb_s[sb][nn] = (sc_s[sb][nn] > thr) ? 1.0f : 0.0f;
    }
    __syncthreads();
    #pragma unroll
    for (int r=0;r<8;++r){
        int i = ts + r*64;
        int n = i>>6, e = i&63;
        float s = 0.f;
        #pragma unroll
        for (int j=0;j<4;++j) s += at_s[sb][n*5+j]*v_s[sb][j*64+e];
        obuf[(size_t)b*512 + i] = (bf16)s;
    }
    if (ts < 8) maskb[b*8+ts] = mb_s[sb][ts];
    float4* mo = (float4*)(mask_out + (size_t)b*4096);
    #pragma unroll
    for (int r=0;r<16;++r){
        int i4 = ts + r*64;
        float m = mb_s[sb][i4>>7];
        float4 mv; mv.x=m; mv.y=m; mv.z=m; mv.w=m;
        mo[i4] = mv;
    }
}

// ---------------------------------------------------------------- xb = o @ ia_fc_w + b (MFMA K=64)
__global__ __launch_bounds__(256) void k_fc_ia(const bf16* __restrict__ obuf,
                                               const bf16* __restrict__ iafcT,
                                               const float* __restrict__ ia_fc_b,
                                               bf16* __restrict__ xb16)
{
    int bx = blockIdx.x, by = blockIdx.y;
    int t = threadIdx.x, w = t>>6, l = t&63, quad = l>>4, l16 = l&15;
    int wm = w&1, wd = w>>1;
    __shared__ bf16 A_s[64*72];
    __shared__ bf16 W_s[64*72];
    #pragma unroll
    for (int j=0;j<2;++j){
        int c = t + j*256;
        int row = c>>3, seg = c&7;
        *(bf16x8*)&A_s[row*72 + seg*8] = *(const bf16x8*)&obuf[((size_t)bx*64+row)*64 + seg*8];
        *(bf16x8*)&W_s[row*72 + seg*8] = *(const bf16x8*)&iafcT[((size_t)by*64+row)*64 + seg*8];
    }
    __syncthreads();
    f32x4 zero = {0.f,0.f,0.f,0.f};
    f32x4 acc[2][2] = {{zero,zero},{zero,zero}};
    #pragma unroll
    for (int k0=0;k0<64;k0+=32){
        bf16x8 a[2], bb[2];
        #pragma unroll
        for (int r=0;r<2;++r) a[r] = *(const bf16x8*)&A_s[(wm*32+r*16+l16)*72 + k0 + quad*8];
        #pragma unroll
        for (int c=0;c<2;++c) bb[c] = *(const bf16x8*)&W_s[(wd*32+c*16+l16)*72 + k0 + quad*8];
        #pragma unroll
        for (int r=0;r<2;++r)
            #pragma unroll
            for (int c=0;c<2;++c)
                acc[r][c] = __builtin_amdgcn_mfma_f32_16x16x32_bf16(a[r], bb[c], acc[r][c], 0,0,0);
    }
    #pragma unroll
    for (int c=0;c<2;++c){
        int col = by*64 + wd*32 + c*16 + l16;
        float bias = ia_fc_b[col];
        #pragma unroll
        for (int r=0;r<2;++r)
            #pragma unroll
            for (int v=0;v<4;++v){
                int row = bx*64 + wm*32 + r*16 + quad*4 + v;
                xb16[(size_t)row*512 + col] = (bf16)(acc[r][c][v] + bias);
            }
    }
}

// ---------------------------------------------------------------- LSTM gates MFMA + pointwise (v6: T3/T4/T5 + 2 blocks/CU)
// 128x256 tile per block (128 rows x [4 gates x 64 d]), 256 threads = 4 waves
// (2 row-halves x 2 gate-pairs). BK=32, 3-deep LDS ring (3 x 24KB = 72KB) ->
// exactly 2 resident blocks/CU (grid 512): independent blocks at different
// phases cover each other's load/barrier stalls (m114 mechanism), which the
// v5 single-block lockstep lacked. Counted vmcnt(6) once per K-tile (never 0
// in-loop); raw s_barrier; setprio around 16-MFMA clusters; XOR-swizzled LDS.
// Epilogue: LDS gather of 4 gates per (row,d) in 2x 64-row chunks -> coalesced
// 256B cx/cx_out/hn16 accesses. bid&7 = n -> XCD affinity.
__global__ __launch_bounds__(256,2) void k_lstm(
    const bf16* __restrict__ xb16, const bf16* __restrict__ hb16,
    const bf16* __restrict__ wT, const float* __restrict__ b_ih,
    const float* __restrict__ b_hh, const float* __restrict__ cx,
    const float* __restrict__ maskb,
    float* __restrict__ cx_out, bf16* __restrict__ hn16)
{
    int bid = blockIdx.x;
    int n  = bid & 7;
    int i  = bid >> 3;          // 0..63
    int mt = i & 7, ct = i >> 3;
    int b0 = mt*128, d0 = ct*64;

    int t = threadIdx.x;
    int w = t >> 6, l = t & 63;
    int wm = w & 1, wg = w >> 1;          // row-half (64 rows), gate-pair (2 gates)
    int quad = l >> 4, l16 = l & 15;

    __shared__ __align__(16) bf16 lds[3*12288];   // 3 bufs x (A 128x32 | B 256x32) = 72 KB

    // ---- staging addresses (per-thread, loop-invariant) ----
    // A: 8 instrs (2/wave), granule G = (w*2+j)*64 + l; row=G>>2; ks=(G&3)^((row>>1)&3)
    int GA0 = (w*2)*64 + l, GA1 = GA0 + 64;
    int rA0 = GA0>>2,       rA1 = GA1>>2;
    int kA0 = (GA0&3) ^ ((rA0>>1)&3);
    int kA1 = (GA1&3) ^ ((rA1>>1)&3);
    const bf16* xbP0 = xb16 + (size_t)(b0+rA0)*4096 + n*512 + kA0*8;
    const bf16* xbP1 = xb16 + (size_t)(b0+rA1)*4096 + n*512 + kA1*8;
    const bf16* hbP0 = hb16 + (size_t)(b0+rA0)*4096 + n*512 + kA0*8;
    const bf16* hbP1 = hb16 + (size_t)(b0+rA1)*4096 + n*512 + kA1*8;

    // B: 16 instrs (4/wave), granule G = (w*4+j)*64 + l; vc=G>>2 (= g*64+dl); ks XOR
    const bf16* wbn = wT + (size_t)n*2048*1024;
    int GB0 = (w*4)*64 + l, GB1 = GB0+64, GB2 = GB0+128, GB3 = GB0+192;
    int vc0 = GB0>>2, vc1 = GB1>>2, vc2 = GB2>>2, vc3 = GB3>>2;
    int kB0 = (GB0&3) ^ ((vc0>>1)&3);
    int kB1 = (GB1&3) ^ ((vc1>>1)&3);
    int kB2 = (GB2&3) ^ ((vc2>>1)&3);
    int kB3 = (GB3&3) ^ ((vc3>>1)&3);
    const bf16* wP0 = wbn + (size_t)((vc0>>6)*512 + d0 + (vc0&63))*1024 + kB0*8;
    const bf16* wP1 = wbn + (size_t)((vc1>>6)*512 + d0 + (vc1&63))*1024 + kB1*8;
    const bf16* wP2 = wbn + (size_t)((vc2>>6)*512 + d0 + (vc2&63))*1024 + kB2*8;
    const bf16* wP3 = wbn + (size_t)((vc3>>6)*512 + d0 + (vc3&63))*1024 + kB3*8;

    // ---- fragment LDS offsets (elems) ----
    int offA[4], offB[8];
    #pragma unroll
    for (int m=0;m<4;++m){ int R = wm*64 + m*16 + l16; offA[m] = (R*4 + (quad ^ ((R>>1)&3)))*8; }
    #pragma unroll
    for (int nf=0;nf<8;++nf){ int C = wg*128 + nf*16 + l16; offB[nf] = 4096 + (C*4 + (quad ^ ((C>>1)&3)))*8; }

    auto stA = [&](int buf, int kt){
        const bf16* s0 = (kt<16 ? xbP0 : hbP0) + (kt&15)*32;
        const bf16* s1 = (kt<16 ? xbP1 : hbP1) + (kt&15)*32;
        bf16* dst = &lds[buf*12288 + (w*2)*512];
        gload16(s0, dst);
        gload16(s1, dst + 512);
    };
    auto stB01 = [&](int buf, int kt){
        bf16* dst = &lds[buf*12288 + 4096 + (w*4)*512];
        gload16(wP0 + (size_t)kt*32, dst);
        gload16(wP1 + (size_t)kt*32, dst + 512);
    };
    auto stB23 = [&](int buf, int kt){
        bf16* dst = &lds[buf*12288 + 4096 + (w*4)*512];
        gload16(wP2 + (size_t)kt*32, dst + 1024);
        gload16(wP3 + (size_t)kt*32, dst + 1536);
    };

    f32x4 zero = {0.f,0.f,0.f,0.f};
    f32x4 acc[4][8];
    #pragma unroll
    for (int m=0;m<4;++m)
        #pragma unroll
        for (int nf=0;nf<8;++nf) acc[m][nf] = zero;

    // ---- prologue: tiles 0,1 in flight (6 loads/wave each); wait oldest 6 ----
    stA(0,0); stB01(0,0); stB23(0,0);
    stA(1,1); stB01(1,1); stB23(1,1);
    WAITVM(6);
    sbar();

    int buf = 0, pbuf = 2;      // (kt+2)%3 == (kt-1)%3 == pbuf
    #pragma unroll 1
    for (int kt=0; kt<32; ++kt){
        const bf16* base = &lds[buf*12288];
        bf16x8 av[4], bv[4];

        // phase 1: gates wg*2 (nf 0..3)
        if (kt < 30){ stA(pbuf, kt+2); stB01(pbuf, kt+2); }
        #pragma unroll
        for (int m=0;m<4;++m) av[m] = *(const bf16x8*)&base[offA[m]];
        #pragma unroll
        for (int nf=0;nf<4;++nf) bv[nf] = *(const bf16x8*)&base[offB[nf]];
        __builtin_amdgcn_s_setprio(1);
        #pragma unroll
        for (int m=0;m<4;++m)
            #pragma unroll
            for (int nf=0;nf<4;++nf)
                acc[m][nf] = __builtin_amdgcn_mfma_f32_16x16x32_bf16(av[m], bv[nf], acc[m][nf], 0,0,0);
        __builtin_amdgcn_s_setprio(0);
        sbar();

        // phase 2: gates wg*2+1 (nf 4..7), reuse A frags
        if (kt < 30) stB23(pbuf, kt+2);
        #pragma unroll
        for (int nf=0;nf<4;++nf) bv[nf] = *(const bf16x8*)&base[offB[4+nf]];
        __builtin_amdgcn_s_setprio(1);
        #pragma unroll
        for (int m=0;m<4;++m)
            #pragma unroll
            for (int nf=0;nf<4;++nf)
                acc[m][4+nf] = __builtin_amdgcn_mfma_f32_16x16x32_bf16(av[m], bv[nf], acc[m][4+nf], 0,0,0);
        __builtin_amdgcn_s_setprio(0);
        // gate tile kt+1: outstanding = kt+1's 6 + kt+2's 6 -> vmcnt(6).
        // kt=30: only tile 31's 6 outstanding -> vmcnt(0) once (pipeline tail).
        if (kt < 30) { WAITVM(6); } else { WAITVM(0); }
        sbar();
        pbuf = buf; buf = (buf==2) ? 0 : buf+1;
    }

    // ---- epilogue: gather 4 gates per (row,d) via LDS, pointwise, coalesced stores ----
    float* gbuf = (float*)lds;          // reuse: 64 x 260 f32 = 66.5 KB <= 72 KB
    const int GP = 260;
    int dl_t = t & 63;
    int i_t  = t >> 6;                  // 0..3 -> 16-row group
    int d = d0 + dl_t;
    float bi  = b_ih[n*2048 +        d] + b_hh[n*2048 +        d];
    float bff = b_ih[n*2048 +  512 + d] + b_hh[n*2048 +  512 + d];
    float bg  = b_ih[n*2048 + 1024 + d] + b_hh[n*2048 + 1024 + d];
    float bo  = b_ih[n*2048 + 1536 + d] + b_hh[n*2048 + 1536 + d];

    #pragma unroll
    for (int c=0; c<2; ++c){            // 64-row chunks
        if (wm == c){
            #pragma unroll
            for (int mm=0; mm<4; ++mm)
                #pragma unroll
                for (int nf=0; nf<8; ++nf)
                    #pragma unroll
                    for (int v=0; v<4; ++v)
                        gbuf[(mm*16 + quad*4 + v)*GP + wg*128 + nf*16 + l16] = acc[mm][nf][v];
        }
        __syncthreads();
        #pragma unroll
        for (int r=0; r<16; ++r){
            int row_l = i_t*16 + r;
            int row_g = b0 + c*64 + row_l;
            float gi = gbuf[row_l*GP +       dl_t] + bi;
            float gf = gbuf[row_l*GP +  64 + dl_t] + bff;
            float gg = gbuf[row_l*GP + 128 + dl_t] + bg;
            float go = gbuf[row_l*GP + 192 + dl_t] + bo;
            size_t gidx = (size_t)row_g*4096 + n*512 + d;
            float cb = cx[gidx];
            float cn = sigf(gf)*cb + sigf(gi)*ftanh(gg);
            float hn = sigf(go)*ftanh(cn);
            float mk = maskb[row_g*8 + n];
            cx_out[gidx] = (mk != 0.f) ? cn : cb;
            hn16[gidx]   = (bf16)hn;
        }
        __syncthreads();
    }
}

// ---------------------------------------------------------------- qkv2 = hn @ mha_w{q,k,v} (MFMA, dbuf)
__global__ __launch_bounds__(256) void k_proj64(const bf16* __restrict__ hn16,
                                                const bf16* __restrict__ wqkvT,
                                                float* __restrict__ qkv2)
{
    int b0 = blockIdx.x*64, n = blockIdx.y, ct = blockIdx.z;
    int t = threadIdx.x, w = t>>6, l = t&63, quad = l>>4, l16 = l&15;
    int wm = w&1, wd = w>>1;
    __shared__ bf16 A_s[2][256*8];
    __shared__ bf16 B_s[2][256*8];
    f32x4 zero = {0.f,0.f,0.f,0.f};
    f32x4 acc[2][2] = {{zero,zero},{zero,zero}};
    const bf16* ab = hn16 + (size_t)n*512;
    const bf16* wb = wqkvT + ((size_t)n*192 + ct*64)*512;

    auto stage = [&](int buf, int k0){
        int row = t>>2, ss = t&3;
        int seg = ss ^ ((row>>1)&3);
        gload16(ab + (size_t)(b0+row)*4096 + k0 + seg*8, &A_s[buf][(w*64)*8]);
        gload16(wb + (size_t)row*512      + k0 + seg*8, &B_s[buf][(w*64)*8]);
    };

    stage(0, 0);
    for (int it=0; it<16; ++it){
        __syncthreads();
        if (it < 15) stage((it+1)&1, (it+1)*32);
        int buf = it&1;
        bf16x8 a[2], bb[2];
        #pragma unroll
        for (int r=0;r<2;++r){
            int row = wm*32 + r*16 + l16;
            int slot = row*4 + (quad ^ ((row>>1)&3));
            a[r] = *(const bf16x8*)&A_s[buf][slot*8];
        }
        #pragma unroll
        for (int c=0;c<2;++c){
            int col = wd*32 + c*16 + l16;
            int slot = col*4 + (quad ^ ((col>>1)&3));
            bb[c] = *(const bf16x8*)&B_s[buf][slot*8];
        }
        #pragma unroll
        for (int r=0;r<2;++r)
            #pragma unroll
            for (int c=0;c<2;++c)
                acc[r][c] = __builtin_amdgcn_mfma_f32_16x16x32_bf16(a[r], bb[c], acc[r][c], 0,0,0);
    }
    #pragma unroll
    for (int c=0;c<2;++c){
        int col = ct*64 + wd*32 + c*16 + l16;
        #pragma unroll
        for (int r=0;r<2;++r)
            #pragma unroll
            for (int v=0;v<4;++v){
                int row = b0 + wm*32 + r*16 + quad*4 + v;
                qkv2[(size_t)row*1536 + n*192 + col] = acc[r][c][v];
            }
    }
}

// ---------------------------------------------------------------- mha attention -> o2 bf16
__global__ __launch_bounds__(256) void k_att2(const float* __restrict__ qkv2,
                                              bf16* __restrict__ o2buf)
{
    int t = threadIdx.x, sb = t>>6, ts = t&63;
    int b = blockIdx.x*4 + sb;
    __shared__ float q_s[4][512];
    __shared__ float k_s[4][512];
    __shared__ float v_s[4][512];
    __shared__ float at_s[4][64];
    #pragma unroll
    for (int r=0;r<8;++r){
        int i = ts + r*64;
        int n = i>>6, e = i&63;
        const float* src = qkv2 + (size_t)b*1536 + n*192;
        q_s[sb][i] = src[e];
        k_s[sb][i] = src[64+e];
        v_s[sb][i] = src[128+e];
    }
    __syncthreads();
    {
        int n = ts>>3, j = ts&7;
        float s = 0.f;
        const float* q = &q_s[sb][n*64];
        const float* k = &k_s[sb][j*64];
        for (int e=0;e<64;++e) s += q[e]*k[e];
        at_s[sb][ts] = s*0.125f;
    }
    __syncthreads();
    if (ts < 8){
        float m = at_s[sb][ts*8];
        for (int j=1;j<8;++j) m = fmaxf(m, at_s[sb][ts*8+j]);
        float ex[8]; float sum=0.f;
        for (int j=0;j<8;++j){ ex[j]=__expf(at_s[sb][ts*8+j]-m); sum+=ex[j]; }
        float inv = 1.f/sum;
        for (int j=0;j<8;++j) at_s[sb][ts*8+j] = ex[j]*inv;
    }
    __syncthreads();
    #pragma unroll
    for (int r=0;r<8;++r){
        int i = ts + r*64;
        int n = i>>6, e = i&63;
        float s = 0.f;
        #pragma unroll
        for (int j=0;j<8;++j) s += at_s[sb][n*8+j]*v_s[sb][j*64+e];
        o2buf[(size_t)b*512 + i] = (bf16)s;
    }
}

// ---------------------------------------------------------------- hx_out = mask ? hn + sig(g)*tanh(f) : hx
// 2 ct tiles per block: grid (128, 8)
__global__ __launch_bounds__(256) void k_fcgate(const bf16* __restrict__ o2buf,
                                                const bf16* __restrict__ fcgT,
                                                const float* __restrict__ fc_b,
                                                const float* __restrict__ gate_b,
                                                const bf16* __restrict__ hn16,
                                                const float* __restrict__ hx,
                                                const float* __restrict__ maskb,
                                                float* __restrict__ hx_out)
{
    int bx = blockIdx.x, ct0 = blockIdx.y*2;
    int t = threadIdx.x, w = t>>6, l = t&63, quad = l>>4, l16 = l&15;
    __shared__ bf16 A_s[64*72];
    __shared__ bf16 W_s[2][64*72];
    #pragma unroll
    for (int j=0;j<2;++j){
        int c = t + j*256;
        int row = c>>3, seg = c&7;
        *(bf16x8*)&A_s[row*72 + seg*8] = *(const bf16x8*)&o2buf[((size_t)bx*64+row)*64 + seg*8];
        *(bf16x8*)&W_s[0][row*72 + seg*8] = *(const bf16x8*)&fcgT[((size_t)ct0*64+row)*64 + seg*8];
        *(bf16x8*)&W_s[1][row*72 + seg*8] = *(const bf16x8*)&fcgT[((size_t)(ct0+1)*64+row)*64 + seg*8];
    }
    __syncthreads();
    f32x4 zero = {0.f,0.f,0.f,0.f};
    #pragma unroll
    for (int cc=0; cc<2; ++cc){
        int ct = ct0 + cc;
        f32x4 acc[4] = {zero,zero,zero,zero};
        #pragma unroll
        for (int k0=0;k0<64;k0+=32){
            bf16x8 a = *(const bf16x8*)&A_s[(w*16+l16)*72 + k0 + quad*8];
            #pragma unroll
            for (int c=0;c<4;++c){
                bf16x8 bb = *(const bf16x8*)&W_s[cc][(c*16+l16)*72 + k0 + quad*8];
                acc[c] = __builtin_amdgcn_mfma_f32_16x16x32_bf16(a, bb, acc[c], 0,0,0);
            }
        }
        #pragma unroll
        for (int c=0;c<2;++c){
            int d = ct*32 + c*16 + l16;
            float fb = fc_b[d], gb = gate_b[d];
            #pragma unroll
            for (int v=0;v<4;++v){
                int row = bx*64 + w*16 + quad*4 + v;
                int b = row>>3, n = row&7;
                size_t idx = (size_t)b*4096 + n*512 + d;
                float f = acc[c][v]   + fb;
                float g = acc[c+2][v] + gb;
                float hn = (float)hn16[idx];
                float m = maskb[row];
                hx_out[idx] = (m != 0.f) ? (hn + sigf(g)*ftanh(f)) : hx[idx];
            }
        }
    }
}

// ----------------------------------------------------------------
extern "C" void kernel_launch(void* const* d_in, const int* in_sizes, int n_in,
                              void* d_out, int out_size, void* d_ws, size_t ws_size,
                              hipStream_t stream)
{
    const float* inp       = (const float*)d_in[0];
    const float* hx        = (const float*)d_in[1];
    const float* cx        = (const float*)d_in[2];
    const float* ia_wq     = (const float*)d_in[3];
    const float* ia_wk     = (const float*)d_in[4];
    const float* ia_wv     = (const float*)d_in[5];
    const float* ia_fc_w   = (const float*)d_in[6];
    const float* ia_fc_b   = (const float*)d_in[7];
    const float* mha_wq    = (const float*)d_in[8];
    const float* mha_wk    = (const float*)d_in[9];
    const float* mha_wv    = (const float*)d_in[10];
    const float* mha_fc_w  = (const float*)d_in[11];
    const float* mha_fc_b  = (const float*)d_in[12];
    const float* mha_gate_w= (const float*)d_in[13];
    const float* mha_gate_b= (const float*)d_in[14];
    const float* w_ih      = (const float*)d_in[15];
    const float* w_hh      = (const float*)d_in[16];
    const float* b_ih      = (const float*)d_in[17];
    const float* b_hh      = (const float*)d_in[18];

    float* hx_out  = (float*)d_out;
    float* cx_out  = hx_out + (size_t)B_*NHID_;
    float* mask_out= cx_out + (size_t)B_*NHID_;

    char* p = (char*)d_ws;
    bf16* wT     = (bf16*)p;               p += (size_t)8*2048*1024*2;   // 32 MB
    bf16* hb16   = (bf16*)p;               p += (size_t)B_*NHID_*2;      // 8 MB
    bf16* xb16   = (bf16*)p;               p += (size_t)B_*NHID_*2;      // 8 MB
    bf16* hn16   = (bf16*)p;               p += (size_t)B_*NHID_*2;      // 8 MB
    bf16* wqkvT  = (bf16*)p;               p += (size_t)8*192*512*2;     // 1.5 MB
    bf16* iafcT  = (bf16*)p;               p += (size_t)512*64*2;        // 64 KB
    bf16* fcgT   = (bf16*)p;               p += (size_t)1024*64*2;       // 128 KB
    float* qbuf  = (float*)p;              p += (size_t)B_*512*4;        // 2 MB
    float* kbuf  = (float*)p;              p += (size_t)B_*256*4;        // 1 MB
    float* vbuf  = (float*)p;              p += (size_t)B_*256*4;        // 1 MB
    bf16* obuf   = (bf16*)p;               p += (size_t)B_*8*64*2;       // 1 MB
    bf16* o2buf  = (bf16*)p;               p += (size_t)B_*8*64*2;       // 1 MB
    float* qkv2  = (float*)p;              p += (size_t)B_*1536*4;       // 6 MB
    float* maskb = (float*)p;              p += (size_t)B_*8*4;          // 32 KB

    hipLaunchKernelGGL(k_prep, dim3(11648), dim3(256), 0, stream,
                       w_ih, w_hh, hx, mha_wq, mha_wk, mha_wv, ia_fc_w, mha_fc_w, mha_gate_w,
                       wT, hb16, wqkvT, iafcT, fcgT);
    hipLaunchKernelGGL(k_qkv, dim3(32,12), dim3(256), 0, stream,
                       hx, inp, ia_wq, ia_wk, ia_wv, qbuf, kbuf, vbuf);
    hipLaunchKernelGGL(k_score, dim3(256), dim3(256), 0, stream,
                       qbuf, kbuf, vbuf, obuf, maskb, mask_out);
    hipLaunchKernelGGL(k_fc_ia, dim3(128,8), dim3(256), 0, stream, obuf, iafcT, ia_fc_b, xb16);
    hipLaunchKernelGGL(k_lstm, dim3(512), dim3(256), 0, stream,
                       xb16, hb16, wT, b_ih, b_hh, cx, maskb, cx_out, hn16);
    hipLaunchKernelGGL(k_proj64, dim3(16,8,3), dim3(256), 0, stream, hn16, wqkvT, qkv2);
    hipLaunchKernelGGL(k_att2, dim3(256), dim3(256), 0, stream, qkv2, o2buf);
    hipLaunchKernelGGL(k_fcgate, dim3(128,8), dim3(256), 0, stream,
                       o2buf, fcgT, mha_fc_b, mha_gate_b, hn16, hx, maskb, hx_out);
}

// Round 4
// 283.373 us; speedup vs baseline: 1.0189x; 1.0189x over previous
//
#include <hip/hip_runtime.h>
#include <hip/hip_bf16.h>

#define B_    1024
#define NHID_ 4096
#define NBO   8
#define BSO   512
#define DK_   64

typedef __bf16 bf16;
typedef __bf16 bf16x2 __attribute__((ext_vector_type(2)));
typedef __bf16 bf16x4 __attribute__((ext_vector_type(4)));
typedef __bf16 bf16x8 __attribute__((ext_vector_type(8)));
typedef float  f32x4  __attribute__((ext_vector_type(4)));

__device__ __forceinline__ float sigf(float x){
    float e = __expf(-x);
    return __builtin_amdgcn_rcpf(1.0f + e);
}
__device__ __forceinline__ float ftanh(float x){
    float e = __expf(2.0f*x);
    return 1.0f - 2.0f*__builtin_amdgcn_rcpf(e + 1.0f);
}

// async global->LDS, 16B per lane; lds dest is wave-uniform base (+lane*16 implicit)
__device__ __forceinline__ void gload16(const void* g, void* lds){
    __builtin_amdgcn_global_load_lds((const __attribute__((address_space(1))) unsigned int*)g,
                                     (__attribute__((address_space(3))) unsigned int*)lds,
                                     16, 0, 0);
}

// raw barrier without the compiler's vmcnt(0) drain; empty asm pins memory ops
__device__ __forceinline__ void sbar(){
    asm volatile("" ::: "memory");
    __builtin_amdgcn_s_barrier();
    asm volatile("" ::: "memory");
}
#define WAITVM(N) asm volatile("s_waitcnt vmcnt(" #N ")" ::: "memory")

// ---------------------------------------------------------------- merged prep:
// blocks < 4096: w_ih/w_hh -> bf16 transposed wT[n][gcol2048][k1024]
// blocks >= 4096: hx->bf16, mha qkv weight transpose, ia_fc transpose, fc|gate paired transpose
__global__ __launch_bounds__(256) void k_prep(
    const float* __restrict__ w_ih, const float* __restrict__ w_hh,
    const float* __restrict__ hx,
    const float* __restrict__ mha_wq, const float* __restrict__ mha_wk,
    const float* __restrict__ mha_wv, const float* __restrict__ ia_fc_w,
    const float* __restrict__ fc_w, const float* __restrict__ gate_w,
    bf16* __restrict__ wT, bf16* __restrict__ hb16, bf16* __restrict__ wqkvT,
    bf16* __restrict__ iafcT, bf16* __restrict__ fcgT)
{
    int bid = blockIdx.x;
    int t = threadIdx.x;
    if (bid < 4096){
        int c0 = (bid & 31)*64;
        int k0 = ((bid>>5)&7)*64;
        int z  = bid>>8;
        int n = z>>1, which = z&1;
        const float* src = (which ? w_hh : w_ih) + (size_t)n*512*2048;
        __shared__ float tile[64][65];
        #pragma unroll
        for (int it=0; it<4; ++it){
            int idx = t + it*256;
            int r = idx>>4, c4 = (idx&15)*4;
            *(float4*)&tile[r][c4] = *(const float4*)&src[(size_t)(k0+r)*2048 + c0 + c4];
        }
        __syncthreads();
        #pragma unroll
        for (int it=0; it<2; ++it){
            int idx = t + it*256;
            int c = idx>>3, r8 = (idx&7)*8;
            bf16x8 v;
            #pragma unroll
            for (int jj=0;jj<8;++jj) v[jj] = (bf16)tile[r8+jj][c];
            *(bf16x8*)&wT[((size_t)n*2048 + c0 + c)*1024 + which*512 + k0 + r8] = v;
        }
        return;
    }
    int gid = (bid-4096)*256 + t;
    if (gid < 1048576){
        float4 v = ((const float4*)hx)[gid];
        bf16x4 o; o.x=(bf16)v.x; o.y=(bf16)v.y; o.z=(bf16)v.z; o.w=(bf16)v.w;
        *(bf16x4*)&hb16[(size_t)gid*4] = o;
        return;
    }
    int e = gid - 1048576;
    if (e < 786432){   // wqkvT[(n*192+c)*512 + k]
        int col = e >> 9, k = e & 511;
        int n = col / 192, c = col - n*192;
        int p = c >> 6, ee = c & 63;
        const float* s = (p==0) ? mha_wq : ((p==1) ? mha_wk : mha_wv);
        wqkvT[e] = (bf16)s[((size_t)n*512 + k)*64 + ee];
        return;
    }
    e -= 786432;
    if (e < 32768){
        int c = e>>6, k = e&63;
        iafcT[e] = (bf16)ia_fc_w[(size_t)k*512 + c];
        return;
    }
    e -= 32768;
    if (e < 65536){
        int cg = e>>6, k = e&63;
        int ct = cg>>6, j = cg&63;
        const float* s = (j<32) ? fc_w : gate_w;
        int col = ct*32 + (j&31);
        fcgT[e] = (bf16)s[(size_t)k*512 + col];
    }
}

// ---------------------------------------------------------------- q / k / v input-attn GEMMs (fp32 exact)
// v2: K-split across blockIdx.z (2 halves) -> 768 blocks, half the serial K-chain.
// Partial sums land in qbufH/kbufH/vbufH[z]; k_score adds the halves at load.
// grid (32 Mtiles of 32 rows, 12, 2): y<8 -> q for n=y; else kv for j=y-8
__global__ __launch_bounds__(256) void k_qkv(const float* __restrict__ hx,
                                             const float* __restrict__ inp,
                                             const float* __restrict__ ia_wq,
                                             const float* __restrict__ ia_wk,
                                             const float* __restrict__ ia_wv,
                                             float* __restrict__ qbufH,
                                             float* __restrict__ kbufH,
                                             float* __restrict__ vbufH)
{
    int b0 = blockIdx.x*32, y = blockIdx.y, z = blockIdx.z, t = threadIdx.x;
    int tx = t&15, ty = t>>4;
    __shared__ float Af[32][36];
    __shared__ float W1[32][68];
    __shared__ float W2[32][68];
    if (y < 8){
        int n = y;
        float acc[2][4] = {};
        for (int k0=z*256; k0<z*256+256; k0+=32){
            { int row=t>>3, c4=(t&7)*4;
              *(float4*)&Af[row][c4] = *(const float4*)&hx[(size_t)(b0+row)*4096 + n*512 + k0 + c4]; }
            #pragma unroll
            for (int j=0;j<2;++j){
                int id = j*256 + t;
                int kk = id>>4, e4 = (id&15)*4;
                *(float4*)&W1[kk][e4] = *(const float4*)&ia_wq[(size_t)n*32768 + (size_t)(k0+kk)*64 + e4];
            }
            __syncthreads();
            #pragma unroll
            for (int kk4=0; kk4<8; ++kk4){
                float4 a0 = *(float4*)&Af[ty*2  ][kk4*4];
                float4 a1 = *(float4*)&Af[ty*2+1][kk4*4];
                #pragma unroll
                for (int j=0;j<4;++j){
                    float4 wv = *(float4*)&W1[kk4*4+j][tx*4];
                    float s0 = (j==0)?a0.x:((j==1)?a0.y:((j==2)?a0.z:a0.w));
                    float s1 = (j==0)?a1.x:((j==1)?a1.y:((j==2)?a1.z:a1.w));
                    acc[0][0]+=s0*wv.x; acc[0][1]+=s0*wv.y; acc[0][2]+=s0*wv.z; acc[0][3]+=s0*wv.w;
                    acc[1][0]+=s1*wv.x; acc[1][1]+=s1*wv.y; acc[1][2]+=s1*wv.z; acc[1][3]+=s1*wv.w;
                }
            }
            __syncthreads();
        }
        #pragma unroll
        for (int r=0;r<2;++r){
            float4 o; o.x=acc[r][0]; o.y=acc[r][1]; o.z=acc[r][2]; o.w=acc[r][3];
            *(float4*)&qbufH[((size_t)(z*B_ + b0+ty*2+r))*512 + n*64 + tx*4] = o;
        }
    } else {
        int jb = y-8;
        float ak[2][4] = {}, av[2][4] = {};
        for (int k0=z*64; k0<z*64+64; k0+=32){
            { int row=t>>3, c4=(t&7)*4;
              *(float4*)&Af[row][c4] = *(const float4*)&inp[(size_t)(b0+row)*512 + jb*128 + k0 + c4]; }
            #pragma unroll
            for (int j=0;j<2;++j){
                int id = j*256 + t;
                int kk = id>>4, e4 = (id&15)*4;
                *(float4*)&W1[kk][e4] = *(const float4*)&ia_wk[(size_t)jb*8192 + (size_t)(k0+kk)*64 + e4];
                *(float4*)&W2[kk][e4] = *(const float4*)&ia_wv[(size_t)jb*8192 + (size_t)(k0+kk)*64 + e4];
            }
            __syncthreads();
            #pragma unroll
            for (int kk4=0; kk4<8; ++kk4){
                float4 a0 = *(float4*)&Af[ty*2  ][kk4*4];
                float4 a1 = *(float4*)&Af[ty*2+1][kk4*4];
                #pragma unroll
                for (int j=0;j<4;++j){
                    float4 wk = *(float4*)&W1[kk4*4+j][tx*4];
                    float4 wv = *(float4*)&W2[kk4*4+j][tx*4];
                    float s0 = (j==0)?a0.x:((j==1)?a0.y:((j==2)?a0.z:a0.w));
                    float s1 = (j==0)?a1.x:((j==1)?a1.y:((j==2)?a1.z:a1.w));
                    ak[0][0]+=s0*wk.x; ak[0][1]+=s0*wk.y; ak[0][2]+=s0*wk.z; ak[0][3]+=s0*wk.w;
                    ak[1][0]+=s1*wk.x; ak[1][1]+=s1*wk.y; ak[1][2]+=s1*wk.z; ak[1][3]+=s1*wk.w;
                    av[0][0]+=s0*wv.x; av[0][1]+=s0*wv.y; av[0][2]+=s0*wv.z; av[0][3]+=s0*wv.w;
                    av[1][0]+=s1*wv.x; av[1][1]+=s1*wv.y; av[1][2]+=s1*wv.z; av[1][3]+=s1*wv.w;
                }
            }
            __syncthreads();
        }
        #pragma unroll
        for (int r=0;r<2;++r){
            float4 ok; ok.x=ak[r][0]; ok.y=ak[r][1]; ok.z=ak[r][2]; ok.w=ak[r][3];
            float4 ov; ov.x=av[r][0]; ov.y=av[r][1]; ov.z=av[r][2]; ov.w=av[r][3];
            *(float4*)&kbufH[((size_t)(z*B_ + b0+ty*2+r))*256 + jb*64 + tx*4] = ok;
            *(float4*)&vbufH[((size_t)(z*B_ + b0+ty*2+r))*256 + jb*64 + tx*4] = ov;
        }
    }
}

// ---------------------------------------------------------------- scores + softmax + top4 + o
// v2: sums the two K-split partials at load; q.k dots wave-parallel
// (8 lanes per n, shfl_xor reduce) instead of 40-lane x 64-iter serial.
__global__ __launch_bounds__(256) void k_score(const float* __restrict__ qbufH,
                                               const float* __restrict__ kbufH,
                                               const float* __restrict__ vbufH,
                                               bf16* __restrict__ obuf,
                                               float* __restrict__ maskb,
                                               float* __restrict__ mask_out)
{
    int t = threadIdx.x, sb = t>>6, ts = t&63;
    int b = blockIdx.x*4 + sb;
    __shared__ float q_s[4][512];
    __shared__ float k_s[4][256];
    __shared__ float v_s[4][256];
    __shared__ float at_s[4][40];
    __shared__ float sc_s[4][8];
    __shared__ float mb_s[4][8];

    #pragma unroll
    for (int r=0;r<8;++r){
        int i = ts + r*64;
        q_s[sb][i] = qbufH[(size_t)b*512 + i] + qbufH[(size_t)(B_+b)*512 + i];
    }
    #pragma unroll
    for (int r=0;r<4;++r){
        int i = ts + r*64;
        k_s[sb][i] = kbufH[(size_t)b*256 + i] + kbufH[(size_t)(B_+b)*256 + i];
        v_s[sb][i] = vbufH[(size_t)b*256 + i] + vbufH[(size_t)(B_+b)*256 + i];
    }
    __syncthreads();
    {
        int n = ts>>3, g = ts&7;
        const float* q = &q_s[sb][n*64];
        #pragma unroll
        for (int j=0;j<4;++j){
            const float* k = &k_s[sb][j*64];
            float s = 0.f;
            #pragma unroll
            for (int e=0;e<8;++e) s += q[g*8+e]*k[g*8+e];
            s += __shfl_xor(s, 1);
            s += __shfl_xor(s, 2);
            s += __shfl_xor(s, 4);
            if (g==0) at_s[sb][n*5+j] = s*0.125f;
        }
        if (g==1) at_s[sb][n*5+4] = 0.f;
    }
    __syncthreads();
    if (ts < 8){
        float m = at_s[sb][ts*5];
        for (int j=1;j<5;++j) m = fmaxf(m, at_s[sb][ts*5+j]);
        float ex[5]; float sum=0.f;
        for (int j=0;j<5;++j){ ex[j]=__expf(at_s[sb][ts*5+j]-m); sum+=ex[j]; }
        float inv = 1.f/sum;
        for (int j=0;j<5;++j) at_s[sb][ts*5+j] = ex[j]*inv;
        sc_s[sb][ts] = ex[0]*inv;
    }
    __syncthreads();
    if (ts == 0){
        float s[8];
        for (int nn=0;nn<8;++nn) s[nn] = sc_s[sb][nn];
        for (int ii=1;ii<8;++ii){ float key=s[ii]; int jj=ii-1;
            while(jj>=0 && s[jj]<key){ s[jj+1]=s[jj]; --jj; } s[jj+1]=key; }
        float thr = s[3]-0.01f;
        for (int nn=0;nn<8;++nn) mb_s[sb][nn] = (sc_s[sb][nn] > thr) ? 1.0f : 0.0f;
    }
    __syncthreads();
    #pragma unroll
    for (int r=0;r<8;++r){
        int i = ts + r*64;
        int n = i>>6, e = i&63;
        float s = 0.f;
        #pragma unroll
        for (int j=0;j<4;++j) s += at_s[sb][n*5+j]*v_s[sb][j*64+e];
        obuf[(size_t)b*512 + i] = (bf16)s;
    }
    if (ts < 8) maskb[b*8+ts] = mb_s[sb][ts];
    float4* mo = (float4*)(mask_out + (size_t)b*4096);
    #pragma unroll
    for (int r=0;r<16;++r){
        int i4 = ts + r*64;
        float m = mb_s[sb][i4>>7];
        float4 mv; mv.x=m; mv.y=m; mv.z=m; mv.w=m;
        mo[i4] = mv;
    }
}

// ---------------------------------------------------------------- xb = o @ ia_fc_w + b (MFMA K=64)
__global__ __launch_bounds__(256) void k_fc_ia(const bf16* __restrict__ obuf,
                                               const bf16* __restrict__ iafcT,
                                               const float* __restrict__ ia_fc_b,
                                               bf16* __restrict__ xb16)
{
    int bx = blockIdx.x, by = blockIdx.y;
    int t = threadIdx.x, w = t>>6, l = t&63, quad = l>>4, l16 = l&15;
    int wm = w&1, wd = w>>1;
    __shared__ bf16 A_s[64*72];
    __shared__ bf16 W_s[64*72];
    #pragma unroll
    for (int j=0;j<2;++j){
        int c = t + j*256;
        int row = c>>3, seg = c&7;
        *(bf16x8*)&A_s[row*72 + seg*8] = *(const bf16x8*)&obuf[((size_t)bx*64+row)*64 + seg*8];
        *(bf16x8*)&W_s[row*72 + seg*8] = *(const bf16x8*)&iafcT[((size_t)by*64+row)*64 + seg*8];
    }
    __syncthreads();
    f32x4 zero = {0.f,0.f,0.f,0.f};
    f32x4 acc[2][2] = {{zero,zero},{zero,zero}};
    #pragma unroll
    for (int k0=0;k0<64;k0+=32){
        bf16x8 a[2], bb[2];
        #pragma unroll
        for (int r=0;r<2;++r) a[r] = *(const bf16x8*)&A_s[(wm*32+r*16+l16)*72 + k0 + quad*8];
        #pragma unroll
        for (int c=0;c<2;++c) bb[c] = *(const bf16x8*)&W_s[(wd*32+c*16+l16)*72 + k0 + quad*8];
        #pragma unroll
        for (int r=0;r<2;++r)
            #pragma unroll
            for (int c=0;c<2;++c)
                acc[r][c] = __builtin_amdgcn_mfma_f32_16x16x32_bf16(a[r], bb[c], acc[r][c], 0,0,0);
    }
    #pragma unroll
    for (int c=0;c<2;++c){
        int col = by*64 + wd*32 + c*16 + l16;
        float bias = ia_fc_b[col];
        #pragma unroll
        for (int r=0;r<2;++r)
            #pragma unroll
            for (int v=0;v<4;++v){
                int row = bx*64 + wm*32 + r*16 + quad*4 + v;
                xb16[(size_t)row*512 + col] = (bf16)(acc[r][c][v] + bias);
            }
    }
}

// ---------------------------------------------------------------- LSTM gates MFMA + pointwise (v6: T3/T4/T5 + 2 blocks/CU)
__global__ __launch_bounds__(256,2) void k_lstm(
    const bf16* __restrict__ xb16, const bf16* __restrict__ hb16,
    const bf16* __restrict__ wT, const float* __restrict__ b_ih,
    const float* __restrict__ b_hh, const float* __restrict__ cx,
    const float* __restrict__ maskb,
    float* __restrict__ cx_out, bf16* __restrict__ hn16)
{
    int bid = blockIdx.x;
    int n  = bid & 7;
    int i  = bid >> 3;          // 0..63
    int mt = i & 7, ct = i >> 3;
    int b0 = mt*128, d0 = ct*64;

    int t = threadIdx.x;
    int w = t >> 6, l = t & 63;
    int wm = w & 1, wg = w >> 1;          // row-half (64 rows), gate-pair (2 gates)
    int quad = l >> 4, l16 = l & 15;

    __shared__ __align__(16) bf16 lds[3*12288];   // 3 bufs x (A 128x32 | B 256x32) = 72 KB

    int GA0 = (w*2)*64 + l, GA1 = GA0 + 64;
    int rA0 = GA0>>2,       rA1 = GA1>>2;
    int kA0 = (GA0&3) ^ ((rA0>>1)&3);
    int kA1 = (GA1&3) ^ ((rA1>>1)&3);
    const bf16* xbP0 = xb16 + (size_t)(b0+rA0)*4096 + n*512 + kA0*8;
    const bf16* xbP1 = xb16 + (size_t)(b0+rA1)*4096 + n*512 + kA1*8;
    const bf16* hbP0 = hb16 + (size_t)(b0+rA0)*4096 + n*512 + kA0*8;
    const bf16* hbP1 = hb16 + (size_t)(b0+rA1)*4096 + n*512 + kA1*8;

    const bf16* wbn = wT + (size_t)n*2048*1024;
    int GB0 = (w*4)*64 + l, GB1 = GB0+64, GB2 = GB0+128, GB3 = GB0+192;
    int vc0 = GB0>>2, vc1 = GB1>>2, vc2 = GB2>>2, vc3 = GB3>>2;
    int kB0 = (GB0&3) ^ ((vc0>>1)&3);
    int kB1 = (GB1&3) ^ ((vc1>>1)&3);
    int kB2 = (GB2&3) ^ ((vc2>>1)&3);
    int kB3 = (GB3&3) ^ ((vc3>>1)&3);
    const bf16* wP0 = wbn + (size_t)((vc0>>6)*512 + d0 + (vc0&63))*1024 + kB0*8;
    const bf16* wP1 = wbn + (size_t)((vc1>>6)*512 + d0 + (vc1&63))*1024 + kB1*8;
    const bf16* wP2 = wbn + (size_t)((vc2>>6)*512 + d0 + (vc2&63))*1024 + kB2*8;
    const bf16* wP3 = wbn + (size_t)((vc3>>6)*512 + d0 + (vc3&63))*1024 + kB3*8;

    int offA[4], offB[8];
    #pragma unroll
    for (int m=0;m<4;++m){ int R = wm*64 + m*16 + l16; offA[m] = (R*4 + (quad ^ ((R>>1)&3)))*8; }
    #pragma unroll
    for (int nf=0;nf<8;++nf){ int C = wg*128 + nf*16 + l16; offB[nf] = 4096 + (C*4 + (quad ^ ((C>>1)&3)))*8; }

    auto stA = [&](int buf, int kt){
        const bf16* s0 = (kt<16 ? xbP0 : hbP0) + (kt&15)*32;
        const bf16* s1 = (kt<16 ? xbP1 : hbP1) + (kt&15)*32;
        bf16* dst = &lds[buf*12288 + (w*2)*512];
        gload16(s0, dst);
        gload16(s1, dst + 512);
    };
    auto stB01 = [&](int buf, int kt){
        bf16* dst = &lds[buf*12288 + 4096 + (w*4)*512];
        gload16(wP0 + (size_t)kt*32, dst);
        gload16(wP1 + (size_t)kt*32, dst + 512);
    };
    auto stB23 = [&](int buf, int kt){
        bf16* dst = &lds[buf*12288 + 4096 + (w*4)*512];
        gload16(wP2 + (size_t)kt*32, dst + 1024);
        gload16(wP3 + (size_t)kt*32, dst + 1536);
    };

    f32x4 zero = {0.f,0.f,0.f,0.f};
    f32x4 acc[4][8];
    #pragma unroll
    for (int m=0;m<4;++m)
        #pragma unroll
        for (int nf=0;nf<8;++nf) acc[m][nf] = zero;

    stA(0,0); stB01(0,0); stB23(0,0);
    stA(1,1); stB01(1,1); stB23(1,1);
    WAITVM(6);
    sbar();

    int buf = 0, pbuf = 2;      // (kt+2)%3 == (kt-1)%3 == pbuf
    #pragma unroll 1
    for (int kt=0; kt<32; ++kt){
        const bf16* base = &lds[buf*12288];
        bf16x8 av[4], bv[4];

        if (kt < 30){ stA(pbuf, kt+2); stB01(pbuf, kt+2); }
        #pragma unroll
        for (int m=0;m<4;++m) av[m] = *(const bf16x8*)&base[offA[m]];
        #pragma unroll
        for (int nf=0;nf<4;++nf) bv[nf] = *(const bf16x8*)&base[offB[nf]];
        __builtin_amdgcn_s_setprio(1);
        #pragma unroll
        for (int m=0;m<4;++m)
            #pragma unroll
            for (int nf=0;nf<4;++nf)
                acc[m][nf] = __builtin_amdgcn_mfma_f32_16x16x32_bf16(av[m], bv[nf], acc[m][nf], 0,0,0);
        __builtin_amdgcn_s_setprio(0);
        sbar();

        if (kt < 30) stB23(pbuf, kt+2);
        #pragma unroll
        for (int nf=0;nf<4;++nf) bv[nf] = *(const bf16x8*)&base[offB[4+nf]];
        __builtin_amdgcn_s_setprio(1);
        #pragma unroll
        for (int m=0;m<4;++m)
            #pragma unroll
            for (int nf=0;nf<4;++nf)
                acc[m][4+nf] = __builtin_amdgcn_mfma_f32_16x16x32_bf16(av[m], bv[nf], acc[m][4+nf], 0,0,0);
        __builtin_amdgcn_s_setprio(0);
        if (kt < 30) { WAITVM(6); } else { WAITVM(0); }
        sbar();
        pbuf = buf; buf = (buf==2) ? 0 : buf+1;
    }

    float* gbuf = (float*)lds;          // reuse: 64 x 260 f32 = 66.5 KB <= 72 KB
    const int GP = 260;
    int dl_t = t & 63;
    int i_t  = t >> 6;                  // 0..3 -> 16-row group
    int d = d0 + dl_t;
    float bi  = b_ih[n*2048 +        d] + b_hh[n*2048 +        d];
    float bff = b_ih[n*2048 +  512 + d] + b_hh[n*2048 +  512 + d];
    float bg  = b_ih[n*2048 + 1024 + d] + b_hh[n*2048 + 1024 + d];
    float bo  = b_ih[n*2048 + 1536 + d] + b_hh[n*2048 + 1536 + d];

    #pragma unroll
    for (int c=0; c<2; ++c){            // 64-row chunks
        if (wm == c){
            #pragma unroll
            for (int mm=0; mm<4; ++mm)
                #pragma unroll
                for (int nf=0; nf<8; ++nf)
                    #pragma unroll
                    for (int v=0; v<4; ++v)
                        gbuf[(mm*16 + quad*4 + v)*GP + wg*128 + nf*16 + l16] = acc[mm][nf][v];
        }
        __syncthreads();
        #pragma unroll
        for (int r=0; r<16; ++r){
            int row_l = i_t*16 + r;
            int row_g = b0 + c*64 + row_l;
            float gi = gbuf[row_l*GP +       dl_t] + bi;
            float gf = gbuf[row_l*GP +  64 + dl_t] + bff;
            float gg = gbuf[row_l*GP + 128 + dl_t] + bg;
            float go = gbuf[row_l*GP + 192 + dl_t] + bo;
            size_t gidx = (size_t)row_g*4096 + n*512 + d;
            float cb = cx[gidx];
            float cn = sigf(gf)*cb + sigf(gi)*ftanh(gg);
            float hn = sigf(go)*ftanh(cn);
            float mk = maskb[row_g*8 + n];
            cx_out[gidx] = (mk != 0.f) ? cn : cb;
            hn16[gidx]   = (bf16)hn;
        }
        __syncthreads();
    }
}

// ---------------------------------------------------------------- qkv2 = hn @ mha_w{q,k,v} (MFMA, dbuf)
__global__ __launch_bounds__(256) void k_proj64(const bf16* __restrict__ hn16,
                                                const bf16* __restrict__ wqkvT,
                                                float* __restrict__ qkv2)
{
    int b0 = blockIdx.x*64, n = blockIdx.y, ct = blockIdx.z;
    int t = threadIdx.x, w = t>>6, l = t&63, quad = l>>4, l16 = l&15;
    int wm = w&1, wd = w>>1;
    __shared__ bf16 A_s[2][256*8];
    __shared__ bf16 B_s[2][256*8];
    f32x4 zero = {0.f,0.f,0.f,0.f};
    f32x4 acc[2][2] = {{zero,zero},{zero,zero}};
    const bf16* ab = hn16 + (size_t)n*512;
    const bf16* wb = wqkvT + ((size_t)n*192 + ct*64)*512;

    auto stage = [&](int buf, int k0){
        int row = t>>2, ss = t&3;
        int seg = ss ^ ((row>>1)&3);
        gload16(ab + (size_t)(b0+row)*4096 + k0 + seg*8, &A_s[buf][(w*64)*8]);
        gload16(wb + (size_t)row*512      + k0 + seg*8, &B_s[buf][(w*64)*8]);
    };

    stage(0, 0);
    for (int it=0; it<16; ++it){
        __syncthreads();
        if (it < 15) stage((it+1)&1, (it+1)*32);
        int buf = it&1;
        bf16x8 a[2], bb[2];
        #pragma unroll
        for (int r=0;r<2;++r){
            int row = wm*32 + r*16 + l16;
            int slot = row*4 + (quad ^ ((row>>1)&3));
            a[r] = *(const bf16x8*)&A_s[buf][slot*8];
        }
        #pragma unroll
        for (int c=0;c<2;++c){
            int col = wd*32 + c*16 + l16;
            int slot = col*4 + (quad ^ ((col>>1)&3));
            bb[c] = *(const bf16x8*)&B_s[buf][slot*8];
        }
        #pragma unroll
        for (int r=0;r<2;++r)
            #pragma unroll
            for (int c=0;c<2;++c)
                acc[r][c] = __builtin_amdgcn_mfma_f32_16x16x32_bf16(a[r], bb[c], acc[r][c], 0,0,0);
    }
    #pragma unroll
    for (int c=0;c<2;++c){
        int col = ct*64 + wd*32 + c*16 + l16;
        #pragma unroll
        for (int r=0;r<2;++r)
            #pragma unroll
            for (int v=0;v<4;++v){
                int row = b0 + wm*32 + r*16 + quad*4 + v;
                qkv2[(size_t)row*1536 + n*192 + col] = acc[r][c][v];
            }
    }
}

// ---------------------------------------------------------------- mha attention -> o2 bf16
// v2: q.k dots wave-parallel (8 lanes per n, shfl_xor reduce)
__global__ __launch_bounds__(256) void k_att2(const float* __restrict__ qkv2,
                                              bf16* __restrict__ o2buf)
{
    int t = threadIdx.x, sb = t>>6, ts = t&63;
    int b = blockIdx.x*4 + sb;
    __shared__ float q_s[4][512];
    __shared__ float k_s[4][512];
    __shared__ float v_s[4][512];
    __shared__ float at_s[4][64];
    #pragma unroll
    for (int r=0;r<8;++r){
        int i = ts + r*64;
        int n = i>>6, e = i&63;
        const float* src = qkv2 + (size_t)b*1536 + n*192;
        q_s[sb][i] = src[e];
        k_s[sb][i] = src[64+e];
        v_s[sb][i] = src[128+e];
    }
    __syncthreads();
    {
        int n = ts>>3, g = ts&7;
        const float* q = &q_s[sb][n*64];
        #pragma unroll
        for (int j=0;j<8;++j){
            const float* k = &k_s[sb][j*64];
            float s = 0.f;
            #pragma unroll
            for (int e=0;e<8;++e) s += q[g*8+e]*k[g*8+e];
            s += __shfl_xor(s, 1);
            s += __shfl_xor(s, 2);
            s += __shfl_xor(s, 4);
            if (g==0) at_s[sb][n*8+j] = s*0.125f;
        }
    }
    __syncthreads();
    if (ts < 8){
        float m = at_s[sb][ts*8];
        for (int j=1;j<8;++j) m = fmaxf(m, at_s[sb][ts*8+j]);
        float ex[8]; float sum=0.f;
        for (int j=0;j<8;++j){ ex[j]=__expf(at_s[sb][ts*8+j]-m); sum+=ex[j]; }
        float inv = 1.f/sum;
        for (int j=0;j<8;++j) at_s[sb][ts*8+j] = ex[j]*inv;
    }
    __syncthreads();
    #pragma unroll
    for (int r=0;r<8;++r){
        int i = ts + r*64;
        int n = i>>6, e = i&63;
        float s = 0.f;
        #pragma unroll
        for (int j=0;j<8;++j) s += at_s[sb][n*8+j]*v_s[sb][j*64+e];
        o2buf[(size_t)b*512 + i] = (bf16)s;
    }
}

// ---------------------------------------------------------------- hx_out = mask ? hn + sig(g)*tanh(f) : hx
// 2 ct tiles per block: grid (128, 8)
__global__ __launch_bounds__(256) void k_fcgate(const bf16* __restrict__ o2buf,
                                                const bf16* __restrict__ fcgT,
                                                const float* __restrict__ fc_b,
                                                const float* __restrict__ gate_b,
                                                const bf16* __restrict__ hn16,
                                                const float* __restrict__ hx,
                                                const float* __restrict__ maskb,
                                                float* __restrict__ hx_out)
{
    int bx = blockIdx.x, ct0 = blockIdx.y*2;
    int t = threadIdx.x, w = t>>6, l = t&63, quad = l>>4, l16 = l&15;
    __shared__ bf16 A_s[64*72];
    __shared__ bf16 W_s[2][64*72];
    #pragma unroll
    for (int j=0;j<2;++j){
        int c = t + j*256;
        int row = c>>3, seg = c&7;
        *(bf16x8*)&A_s[row*72 + seg*8] = *(const bf16x8*)&o2buf[((size_t)bx*64+row)*64 + seg*8];
        *(bf16x8*)&W_s[0][row*72 + seg*8] = *(const bf16x8*)&fcgT[((size_t)ct0*64+row)*64 + seg*8];
        *(bf16x8*)&W_s[1][row*72 + seg*8] = *(const bf16x8*)&fcgT[((size_t)(ct0+1)*64+row)*64 + seg*8];
    }
    __syncthreads();
    f32x4 zero = {0.f,0.f,0.f,0.f};
    #pragma unroll
    for (int cc=0; cc<2; ++cc){
        int ct = ct0 + cc;
        f32x4 acc[4] = {zero,zero,zero,zero};
        #pragma unroll
        for (int k0=0;k0<64;k0+=32){
            bf16x8 a = *(const bf16x8*)&A_s[(w*16+l16)*72 + k0 + quad*8];
            #pragma unroll
            for (int c=0;c<4;++c){
                bf16x8 bb = *(const bf16x8*)&W_s[cc][(c*16+l16)*72 + k0 + quad*8];
                acc[c] = __builtin_amdgcn_mfma_f32_16x16x32_bf16(a, bb, acc[c], 0,0,0);
            }
        }
        #pragma unroll
        for (int c=0;c<2;++c){
            int d = ct*32 + c*16 + l16;
            float fb = fc_b[d], gb = gate_b[d];
            #pragma unroll
            for (int v=0;v<4;++v){
                int row = bx*64 + w*16 + quad*4 + v;
                int b = row>>3, n = row&7;
                size_t idx = (size_t)b*4096 + n*512 + d;
                float f = acc[c][v]   + fb;
                float g = acc[c+2][v] + gb;
                float hn = (float)hn16[idx];
                float m = maskb[row];
                hx_out[idx] = (m != 0.f) ? (hn + sigf(g)*ftanh(f)) : hx[idx];
            }
        }
    }
}

// ----------------------------------------------------------------
extern "C" void kernel_launch(void* const* d_in, const int* in_sizes, int n_in,
                              void* d_out, int out_size, void* d_ws, size_t ws_size,
                              hipStream_t stream)
{
    const float* inp       = (const float*)d_in[0];
    const float* hx        = (const float*)d_in[1];
    const float* cx        = (const float*)d_in[2];
    const float* ia_wq     = (const float*)d_in[3];
    const float* ia_wk     = (const float*)d_in[4];
    const float* ia_wv     = (const float*)d_in[5];
    const float* ia_fc_w   = (const float*)d_in[6];
    const float* ia_fc_b   = (const float*)d_in[7];
    const float* mha_wq    = (const float*)d_in[8];
    const float* mha_wk    = (const float*)d_in[9];
    const float* mha_wv    = (const float*)d_in[10];
    const float* mha_fc_w  = (const float*)d_in[11];
    const float* mha_fc_b  = (const float*)d_in[12];
    const float* mha_gate_w= (const float*)d_in[13];
    const float* mha_gate_b= (const float*)d_in[14];
    const float* w_ih      = (const float*)d_in[15];
    const float* w_hh      = (const float*)d_in[16];
    const float* b_ih      = (const float*)d_in[17];
    const float* b_hh      = (const float*)d_in[18];

    float* hx_out  = (float*)d_out;
    float* cx_out  = hx_out + (size_t)B_*NHID_;
    float* mask_out= cx_out + (size_t)B_*NHID_;

    char* p = (char*)d_ws;
    bf16* wT     = (bf16*)p;               p += (size_t)8*2048*1024*2;   // 32 MB
    bf16* hb16   = (bf16*)p;               p += (size_t)B_*NHID_*2;      // 8 MB
    bf16* xb16   = (bf16*)p;               p += (size_t)B_*NHID_*2;      // 8 MB
    bf16* hn16   = (bf16*)p;               p += (size_t)B_*NHID_*2;      // 8 MB
    bf16* wqkvT  = (bf16*)p;               p += (size_t)8*192*512*2;     // 1.5 MB
    bf16* iafcT  = (bf16*)p;               p += (size_t)512*64*2;        // 64 KB
    bf16* fcgT   = (bf16*)p;               p += (size_t)1024*64*2;       // 128 KB
    float* qbufH = (float*)p;              p += (size_t)2*B_*512*4;      // 4 MB (2 K-halves)
    float* kbufH = (float*)p;              p += (size_t)2*B_*256*4;      // 2 MB
    float* vbufH = (float*)p;              p += (size_t)2*B_*256*4;      // 2 MB
    bf16* obuf   = (bf16*)p;               p += (size_t)B_*8*64*2;       // 1 MB
    bf16* o2buf  = (bf16*)p;               p += (size_t)B_*8*64*2;       // 1 MB
    float* qkv2  = (float*)p;              p += (size_t)B_*1536*4;       // 6 MB
    float* maskb = (float*)p;              p += (size_t)B_*8*4;          // 32 KB

    hipLaunchKernelGGL(k_prep, dim3(11648), dim3(256), 0, stream,
                       w_ih, w_hh, hx, mha_wq, mha_wk, mha_wv, ia_fc_w, mha_fc_w, mha_gate_w,
                       wT, hb16, wqkvT, iafcT, fcgT);
    hipLaunchKernelGGL(k_qkv, dim3(32,12,2), dim3(256), 0, stream,
                       hx, inp, ia_wq, ia_wk, ia_wv, qbufH, kbufH, vbufH);
    hipLaunchKernelGGL(k_score, dim3(256), dim3(256), 0, stream,
                       qbufH, kbufH, vbufH, obuf, maskb, mask_out);
    hipLaunchKernelGGL(k_fc_ia, dim3(128,8), dim3(256), 0, stream, obuf, iafcT, ia_fc_b, xb16);
    hipLaunchKernelGGL(k_lstm, dim3(512), dim3(256), 0, stream,
                       xb16, hb16, wT, b_ih, b_hh, cx, maskb, cx_out, hn16);
    hipLaunchKernelGGL(k_proj64, dim3(16,8,3), dim3(256), 0, stream, hn16, wqkvT, qkv2);
    hipLaunchKernelGGL(k_att2, dim3(256), dim3(256), 0, stream, qkv2, o2buf);
    hipLaunchKernelGGL(k_fcgate, dim3(128,8), dim3(256), 0, stream,
                       o2buf, fcgT, mha_fc_b, mha_gate_b, hn16, hx, maskb, hx_out);
}